// Round 21
// baseline (103.595 us; speedup 1.0000x reference)
//
#include <hip/hip_runtime.h>
#include <hip/hip_bf16.h>

#define NB 16384
#define NH 50

typedef __attribute__((ext_vector_type(4))) float        f32x4;
typedef __attribute__((ext_vector_type(8))) short        s16x8;
typedef __attribute__((ext_vector_type(4))) unsigned int u32x4;

// ws layout (floats):
//   bfrag (u32) : [0, 8192)        32 KB  — W hi/lo bf16 MFMA fragments
//   user_vec    : [6400000, +1M)   4.2 MB
//   target_rep  : [7448576, +1M)   4.2 MB

__device__ __forceinline__ unsigned rne16(float x) {
  unsigned u = __float_as_uint(x);
  return (u + 0x7FFFu + ((u >> 16) & 1u)) >> 16;
}

__device__ __forceinline__ unsigned pk_bf16(float r0, float r1) {
  __hip_bfloat162 h = __float22bfloat162_rn(make_float2(r0, r1));  // v_cvt_pk_bf16_f32
  unsigned u;
  __builtin_memcpy(&u, &h, 4);
  return u;
}

// trunc-hi split: x = hi + r exactly (hi = upper-16 bits, bf16-representable);
// lo = rne(r).
__device__ __forceinline__ void cvt8t(const f32x4 a, const f32x4 b, u32x4& hi, u32x4& lo) {
  unsigned ha[8]; float r[8];
#pragma unroll
  for (int i = 0; i < 4; ++i) {
    const unsigned ua = __float_as_uint(a[i]) & 0xFFFF0000u;
    ha[i] = ua; r[i] = a[i] - __uint_as_float(ua);
  }
#pragma unroll
  for (int i = 0; i < 4; ++i) {
    const unsigned ub = __float_as_uint(b[i]) & 0xFFFF0000u;
    ha[4 + i] = ub; r[4 + i] = b[i] - __uint_as_float(ub);
  }
#pragma unroll
  for (int p = 0; p < 4; ++p) {
    hi[p] = ha[2 * p + 1] | (ha[2 * p] >> 16);   // elem 2p -> low16, 2p+1 -> high16
    lo[p] = pk_bf16(r[2 * p], r[2 * p + 1]);
  }
}

// ---------------- kernel W: build bf16 hi/lo B-fragments of fusion_w ----------------
// frag set f = (ks<<3)|(nt<<1)|sp ; lane l ; dword j : B[ks*32+(l>>4)*8+2j(+1)][nt*16+(l&15)]
__global__ __launch_bounds__(256) void wprep_k(const float* __restrict__ fw,
                                               unsigned* __restrict__ bfrag) {
  const int d = blockIdx.x * 256 + threadIdx.x;   // 0..8191
  const int j = d & 3, l = (d >> 2) & 63, f = d >> 8;
  const int sp = f & 1, nt = (f >> 1) & 3, ks = f >> 3;
  const int n  = nt * 16 + (l & 15);
  const int k0 = ks * 32 + (l >> 4) * 8 + 2 * j;
  const float w0 = fw[k0 * 64 + n], w1 = fw[(k0 + 1) * 64 + n];
  const unsigned h0 = rne16(w0), h1 = rne16(w1);
  unsigned dw;
  if (sp == 0) dw = h0 | (h1 << 16);
  else {
    const float r0 = w0 - __uint_as_float(h0 << 16);
    const float r1 = w1 - __uint_as_float(h1 << 16);
    dw = rne16(r0) | (rne16(r1) << 16);
  }
  bfrag[d] = dw;
}

// ---------------- kernel B: MFMA item-rep + pooling ----------------
// R14 discipline (B in LDS, 3 waves/SIMD, sched_barrier per tile) with
// ASYMMETRIC prefetch: emb gathers (scattered, latency-dominated) 2-deep,
// hfeat stream (coalesced) 1-deep. +16 buffer regs vs R14.
__global__ __launch_bounds__(256, 3) void pool_mfma_k(
    const int* __restrict__ hidx, const float* __restrict__ hfeat,
    const float* __restrict__ hrat, const int* __restrict__ tidx,
    const float* __restrict__ tfeat, const float* __restrict__ table,
    const float* __restrict__ fb, const unsigned* __restrict__ bfrag,
    float* __restrict__ user_vec, float* __restrict__ target_rep)
{
  __shared__ u32x4 sB[2048];   // 32 KB: frag f in 0..31, lane l: sB[f*64 + l]
  const int tid = threadIdx.x;
  {
    const u32x4* src = (const u32x4*)bfrag;
#pragma unroll
    for (int k = 0; k < 8; ++k) sB[tid + k * 256] = src[tid + k * 256];
  }

  const int l  = tid & 63;
  const int wv = tid >> 6;
  const int wave = (blockIdx.x << 2) + wv;          // 0..8191
  const int lm = l & 15, lg = l >> 4;
  const int b0 = wave, b1 = wave + 8192;

  // coalesced headers for BOTH batches
  const int r_l = (l < NH) ? l : (NH - 1);
  int idxv0 = hidx[(size_t)b0 * NH + r_l];
  int idxv1 = hidx[(size_t)b1 * NH + r_l];
  float rat0 = (l < NH) ? (hrat[(size_t)b0 * NH + l] - 3.0f) : 0.f;
  float rat1 = (l < NH) ? (hrat[(size_t)b1 * NH + l] - 3.0f) : 0.f;
  if (l == NH) { idxv0 = tidx[b0]; idxv1 = tidx[b1]; }   // lane 50 carries target

  float bias[4];
#pragma unroll
  for (int nt = 0; nt < 4; ++nt) bias[nt] = fb[nt * 16 + lm];

  __syncthreads();   // sB ready

  // emb gathers for tile i (scattered 64B/lane from the cached table)
  auto load_emb = [&](int i, f32x4* qe) {
    const int rep = i >> 2, m = i & 3;
    const int mi  = rep ? idxv1 : idxv0;
    const int r   = m * 16 + lm;
    const int sel = (r <= NH) ? r : (NH - 1);
    const int idxm = __shfl(mi, sel, 64);
    const float* ep = table + (size_t)idxm * 64;
    qe[0] = *(const f32x4*)(ep + lg * 8);
    qe[1] = *(const f32x4*)(ep + lg * 8 + 4);
    qe[2] = *(const f32x4*)(ep + 32 + lg * 8);
    qe[3] = *(const f32x4*)(ep + 32 + lg * 8 + 4);
  };
  // hfeat stream for tile i (coalesced)
  auto load_feat = [&](int i, f32x4* qf) {
    const int rep = i >> 2, m = i & 3;
    const int bb  = rep ? b1 : b0;
    const int r   = m * 16 + lm;
    const float* fp = (r < NH) ? (hfeat + ((size_t)bb * NH + r) * 64)
                    : (r == NH) ? (tfeat + (size_t)bb * 64)
                                : (hfeat + ((size_t)bb * NH + (NH - 1)) * 64);
    qf[0] = *(const f32x4*)(fp + lg * 8);
    qf[1] = *(const f32x4*)(fp + lg * 8 + 4);
    qf[2] = *(const f32x4*)(fp + 32 + lg * 8);
    qf[3] = *(const f32x4*)(fp + 32 + lg * 8 + 4);
  };

  f32x4 qeA[4], qeB[4], qeC[4];   // emb: 2-deep (3 buffers)
  f32x4 qfA[4], qfB[4];           // feat: 1-deep (2 buffers)
  load_emb(0, qeA);
  load_emb(1, qeB);
  load_feat(0, qfA);

  float uacc[4] = {0.f, 0.f, 0.f, 0.f};
  float trep[4] = {0.f, 0.f, 0.f, 0.f};

#pragma unroll
  for (int i = 0; i < 8; ++i) {
    const int rep = i >> 2, m = i & 3;
    // fully unrolled -> all buffer selections compile-time
    f32x4* qec = (i % 3 == 0) ? qeA : (i % 3 == 1) ? qeB : qeC;
    f32x4* qen = ((i + 2) % 3 == 0) ? qeA : ((i + 2) % 3 == 1) ? qeB : qeC;
    f32x4* qfc = (i & 1) ? qfB : qfA;
    f32x4* qfn = (i & 1) ? qfA : qfB;

    // issue prefetches first: emb for i+2 (2 tiles of cover), feat for i+1
    if (i < 6) load_emb(i + 2, qen);
    if (i < 7) load_feat(i + 1, qfn);

    // convert current tile (qec/qfc die here)
    u32x4 ahi[4], alo[4];
    cvt8t(qec[0], qec[1], ahi[0], alo[0]);
    cvt8t(qec[2], qec[3], ahi[1], alo[1]);
    cvt8t(qfc[0], qfc[1], ahi[2], alo[2]);
    cvt8t(qfc[2], qfc[3], ahi[3], alo[3]);

    f32x4 acc[4];
#pragma unroll
    for (int nt = 0; nt < 4; ++nt) {
      const float bv = bias[nt];
      acc[nt] = (f32x4){bv, bv, bv, bv};
    }
#pragma unroll
    for (int ks = 0; ks < 4; ++ks) {
      const s16x8 ah = __builtin_bit_cast(s16x8, ahi[ks]);
      const s16x8 al = __builtin_bit_cast(s16x8, alo[ks]);
#pragma unroll
      for (int nt = 0; nt < 4; ++nt) {
        const s16x8 bh = __builtin_bit_cast(s16x8, sB[((ks * 8 + nt * 2 + 0) * 64) + l]);
        const s16x8 bl = __builtin_bit_cast(s16x8, sB[((ks * 8 + nt * 2 + 1) * 64) + l]);
        acc[nt] = __builtin_amdgcn_mfma_f32_16x16x32_bf16(ah, bh, acc[nt], 0, 0, 0);
        acc[nt] = __builtin_amdgcn_mfma_f32_16x16x32_bf16(al, bh, acc[nt], 0, 0, 0);
        acc[nt] = __builtin_amdgcn_mfma_f32_16x16x32_bf16(ah, bl, acc[nt], 0, 0, 0);
      }
    }

    // epilogue: relu + weighted pooling ; C layout: col=lm+16nt, row=m*16+lg*4+e
    const float rw_all = rep ? rat1 : rat0;
#pragma unroll
    for (int e = 0; e < 4; ++e) {
      const int rr = m * 16 + lg * 4 + e;
      const float w = __shfl(rw_all, rr, 64);
#pragma unroll
      for (int nt = 0; nt < 4; ++nt) {
        const float repv = fmaxf(acc[nt][e], 0.f);
        uacc[nt] = fmaf(w, repv, uacc[nt]);
        if (m == 3 && e == 2) trep[nt] = repv;   // row 50 = target (valid on lg==0)
      }
    }

    if (m == 3) {
      // finalize this batch
      const int bb = rep ? b1 : b0;
      float den = fabsf(rw_all);
#pragma unroll
      for (int s = 32; s >= 1; s >>= 1) den += __shfl_xor(den, s, 64);
#pragma unroll
      for (int nt = 0; nt < 4; ++nt) {
        uacc[nt] += __shfl_xor(uacc[nt], 16, 64);
        uacc[nt] += __shfl_xor(uacc[nt], 32, 64);
      }
      const float dinv = den + 1e-8f;
      const float usel = (lg == 0) ? uacc[0] : (lg == 1) ? uacc[1]
                       : (lg == 2) ? uacc[2] : uacc[3];
      user_vec[(size_t)bb * 64 + l] = usel / dinv;
      if (l < 16) {
        float* tp = target_rep + (size_t)bb * 64 + l;
        tp[0]  = trep[0];
        tp[16] = trep[1];
        tp[32] = trep[2];
        tp[48] = trep[3];
      }
#pragma unroll
      for (int nt = 0; nt < 4; ++nt) { uacc[nt] = 0.f; trep[nt] = 0.f; }
    }

    // cap scheduler pressure: no cross-tile hoisting bulges
    __builtin_amdgcn_sched_barrier(0);
  }
}

// ---------------- kernel C: rating MLP ----------------
__global__ __launch_bounds__(256) void mlp_k(
    const float* __restrict__ user_vec, const float* __restrict__ target_rep,
    const float* __restrict__ w1, const float* __restrict__ b1,
    const float* __restrict__ w2, const float* __restrict__ b2,
    const float* __restrict__ w3, const float* __restrict__ b3,
    float* __restrict__ out)
{
  __shared__ alignas(16) float s_w1[128 * 64];  // 32 KB
  __shared__ alignas(16) float s_w2[64 * 32];   //  8 KB
  __shared__ float s_w3[32];
  __shared__ alignas(16) float s_x[4][128];
  __shared__ alignas(16) float s_h1[4][64];
  const int tid = threadIdx.x;
  for (int i = tid; i < 128 * 64; i += 256) s_w1[i] = w1[i];
  for (int i = tid; i < 64 * 32;  i += 256) s_w2[i] = w2[i];
  if (tid < 32) s_w3[tid] = w3[tid];
  __syncthreads();

  const int t  = tid & 63;
  const int wv = tid >> 6;
  const int nwaves = gridDim.x << 2;
  const float b1t = b1[t];
  const float bb3 = b3[0];
  const int n2 = t & 31;
  const float b2n = b2[n2];
  for (int b = (blockIdx.x << 2) + wv; b < NB; b += nwaves) {
    s_x[wv][t]      = user_vec[(size_t)b * 64 + t];
    s_x[wv][64 + t] = target_rep[(size_t)b * 64 + t];
    float a0 = b1t, a1 = 0.f, a2 = 0.f, a3 = 0.f;
#pragma unroll
    for (int k4 = 0; k4 < 32; ++k4) {
      float4 x = *reinterpret_cast<const float4*>(&s_x[wv][k4 * 4]);
      a0 = fmaf(x.x, s_w1[(4 * k4 + 0) * 64 + t], a0);
      a1 = fmaf(x.y, s_w1[(4 * k4 + 1) * 64 + t], a1);
      a2 = fmaf(x.z, s_w1[(4 * k4 + 2) * 64 + t], a2);
      a3 = fmaf(x.w, s_w1[(4 * k4 + 3) * 64 + t], a3);
    }
    s_h1[wv][t] = fmaxf((a0 + a1) + (a2 + a3), 0.f);
    float c0 = b2n, c1 = 0.f, c2 = 0.f, c3 = 0.f;
#pragma unroll
    for (int k4 = 0; k4 < 16; ++k4) {
      float4 x = *reinterpret_cast<const float4*>(&s_h1[wv][k4 * 4]);
      c0 = fmaf(x.x, s_w2[(4 * k4 + 0) * 32 + n2], c0);
      c1 = fmaf(x.y, s_w2[(4 * k4 + 1) * 32 + n2], c1);
      c2 = fmaf(x.z, s_w2[(4 * k4 + 2) * 32 + n2], c2);
      c3 = fmaf(x.w, s_w2[(4 * k4 + 3) * 32 + n2], c3);
    }
    const float h2 = fmaxf((c0 + c1) + (c2 + c3), 0.f);
    float p = (t < 32) ? h2 * s_w3[n2] : 0.f;
#pragma unroll
    for (int m = 32; m >= 1; m >>= 1) p += __shfl_xor(p, m, 64);
    if (t == 0) out[b] = p + bb3;
  }
}

extern "C" void kernel_launch(void* const* d_in, const int* in_sizes, int n_in,
                              void* d_out, int out_size, void* d_ws, size_t ws_size,
                              hipStream_t stream) {
  const int*   hidx  = (const int*)  d_in[0];
  const float* hfeat = (const float*)d_in[1];
  const float* hrat  = (const float*)d_in[2];
  const int*   tidx  = (const int*)  d_in[3];
  const float* tfeat = (const float*)d_in[4];
  const float* table = (const float*)d_in[5];
  const float* fw    = (const float*)d_in[6];
  const float* fb    = (const float*)d_in[7];
  const float* w1    = (const float*)d_in[8];
  const float* b1    = (const float*)d_in[9];
  const float* w2    = (const float*)d_in[10];
  const float* b2    = (const float*)d_in[11];
  const float* w3    = (const float*)d_in[12];
  const float* b3    = (const float*)d_in[13];
  float* out = (float*)d_out;
  float* ws  = (float*)d_ws;
  unsigned* bfrag   = (unsigned*)ws;      // 8192 dwords
  float* user_vec   = ws + 6400000;
  float* target_rep = ws + 7448576;

  hipLaunchKernelGGL(wprep_k, dim3(32), dim3(256), 0, stream, fw, bfrag);
  hipLaunchKernelGGL(pool_mfma_k, dim3(2048), dim3(256), 0, stream,
                     hidx, hfeat, hrat, tidx, tfeat, table, fb, bfrag,
                     user_vec, target_rep);
  hipLaunchKernelGGL(mlp_k, dim3(512), dim3(256), 0, stream,
                     user_vec, target_rep, w1, b1, w2, b2, w3, b3, out);
}

// Round 22
// 99.561 us; speedup vs baseline: 1.0405x; 1.0405x over previous
//
#include <hip/hip_runtime.h>
#include <hip/hip_bf16.h>

#define NB 16384
#define NH 50

typedef __attribute__((ext_vector_type(4))) float        f32x4;
typedef __attribute__((ext_vector_type(8))) short        s16x8;
typedef __attribute__((ext_vector_type(4))) unsigned int u32x4;

// ws layout (floats):
//   bfrag (u32) : [0, 8192)        32 KB  — W hi/lo bf16 MFMA fragments
//   user_vec    : [6400000, +1M)   4.2 MB
//   target_rep  : [7448576, +1M)   4.2 MB

__device__ __forceinline__ unsigned rne16(float x) {
  unsigned u = __float_as_uint(x);
  return (u + 0x7FFFu + ((u >> 16) & 1u)) >> 16;
}

__device__ __forceinline__ unsigned pk_bf16(float r0, float r1) {
  __hip_bfloat162 h = __float22bfloat162_rn(make_float2(r0, r1));  // v_cvt_pk_bf16_f32
  unsigned u;
  __builtin_memcpy(&u, &h, 4);
  return u;
}

// trunc-hi split: x = hi + r exactly (hi = upper-16 bits, bf16-representable);
// lo = rne(r).
__device__ __forceinline__ void cvt8t(const f32x4 a, const f32x4 b, u32x4& hi, u32x4& lo) {
  unsigned ha[8]; float r[8];
#pragma unroll
  for (int i = 0; i < 4; ++i) {
    const unsigned ua = __float_as_uint(a[i]) & 0xFFFF0000u;
    ha[i] = ua; r[i] = a[i] - __uint_as_float(ua);
  }
#pragma unroll
  for (int i = 0; i < 4; ++i) {
    const unsigned ub = __float_as_uint(b[i]) & 0xFFFF0000u;
    ha[4 + i] = ub; r[4 + i] = b[i] - __uint_as_float(ub);
  }
#pragma unroll
  for (int p = 0; p < 4; ++p) {
    hi[p] = ha[2 * p + 1] | (ha[2 * p] >> 16);   // elem 2p -> low16, 2p+1 -> high16
    lo[p] = pk_bf16(r[2 * p], r[2 * p + 1]);
  }
}

// ---------------- kernel W: build bf16 hi/lo B-fragments of fusion_w ----------------
// frag set f = (ks<<3)|(nt<<1)|sp ; lane l ; dword j : B[ks*32+(l>>4)*8+2j(+1)][nt*16+(l&15)]
__global__ __launch_bounds__(256) void wprep_k(const float* __restrict__ fw,
                                               unsigned* __restrict__ bfrag) {
  const int d = blockIdx.x * 256 + threadIdx.x;   // 0..8191
  const int j = d & 3, l = (d >> 2) & 63, f = d >> 8;
  const int sp = f & 1, nt = (f >> 1) & 3, ks = f >> 3;
  const int n  = nt * 16 + (l & 15);
  const int k0 = ks * 32 + (l >> 4) * 8 + 2 * j;
  const float w0 = fw[k0 * 64 + n], w1 = fw[(k0 + 1) * 64 + n];
  const unsigned h0 = rne16(w0), h1 = rne16(w1);
  unsigned dw;
  if (sp == 0) dw = h0 | (h1 << 16);
  else {
    const float r0 = w0 - __uint_as_float(h0 << 16);
    const float r1 = w1 - __uint_as_float(h1 << 16);
    dw = rne16(r0) | (rne16(r1) << 16);
  }
  bfrag[d] = dw;
}

// ---------------- kernel B: MFMA item-rep + pooling ----------------
// B in LDS + 3 waves/SIMD + sched_barrier per tile (spill-free) +
// 1-deep qA/qB prefetch pipeline. Measured optimum of the config matrix
// (R8..R21): every neighboring config (4/SIMD, 2-deep, asymmetric-deep,
// 2-batch fusion, K=64 restructure, prepacked table) is worse via spills,
// pressure, TLP loss, or gather scatter.
__global__ __launch_bounds__(256, 3) void pool_mfma_k(
    const int* __restrict__ hidx, const float* __restrict__ hfeat,
    const float* __restrict__ hrat, const int* __restrict__ tidx,
    const float* __restrict__ tfeat, const float* __restrict__ table,
    const float* __restrict__ fb, const unsigned* __restrict__ bfrag,
    float* __restrict__ user_vec, float* __restrict__ target_rep)
{
  __shared__ u32x4 sB[2048];   // 32 KB: frag f in 0..31, lane l: sB[f*64 + l]
  const int tid = threadIdx.x;
  {
    const u32x4* src = (const u32x4*)bfrag;
#pragma unroll
    for (int k = 0; k < 8; ++k) sB[tid + k * 256] = src[tid + k * 256];
  }

  const int l  = tid & 63;
  const int wv = tid >> 6;
  const int wave = (blockIdx.x << 2) + wv;          // 0..8191
  const int lm = l & 15, lg = l >> 4;
  const int b0 = wave, b1 = wave + 8192;

  // coalesced headers for BOTH batches
  const int r_l = (l < NH) ? l : (NH - 1);
  int idxv0 = hidx[(size_t)b0 * NH + r_l];
  int idxv1 = hidx[(size_t)b1 * NH + r_l];
  float rat0 = (l < NH) ? (hrat[(size_t)b0 * NH + l] - 3.0f) : 0.f;
  float rat1 = (l < NH) ? (hrat[(size_t)b1 * NH + l] - 3.0f) : 0.f;
  if (l == NH) { idxv0 = tidx[b0]; idxv1 = tidx[b1]; }   // lane 50 carries target

  float bias[4];
#pragma unroll
  for (int nt = 0; nt < 4; ++nt) bias[nt] = fb[nt * 16 + lm];

  __syncthreads();   // sB ready

  // tile i (i = rep*4 + m): load A-rows for 16x128 sub-tile into q[8]
  auto load_tile = [&](int i, f32x4* q) {
    const int rep = i >> 2, m = i & 3;
    const int bb  = rep ? b1 : b0;
    const int mi  = rep ? idxv1 : idxv0;
    const int r   = m * 16 + lm;
    const int sel = (r <= NH) ? r : (NH - 1);
    const int idxm = __shfl(mi, sel, 64);
    const float* fp = (r < NH) ? (hfeat + ((size_t)bb * NH + r) * 64)
                    : (r == NH) ? (tfeat + (size_t)bb * 64)
                                : (hfeat + ((size_t)bb * NH + (NH - 1)) * 64);
    const float* ep = table + (size_t)idxm * 64;
    q[0] = *(const f32x4*)(ep + lg * 8);
    q[1] = *(const f32x4*)(ep + lg * 8 + 4);
    q[2] = *(const f32x4*)(ep + 32 + lg * 8);
    q[3] = *(const f32x4*)(ep + 32 + lg * 8 + 4);
    q[4] = *(const f32x4*)(fp + lg * 8);
    q[5] = *(const f32x4*)(fp + lg * 8 + 4);
    q[6] = *(const f32x4*)(fp + 32 + lg * 8);
    q[7] = *(const f32x4*)(fp + 32 + lg * 8 + 4);
  };

  f32x4 qA[8], qB[8];
  load_tile(0, qA);

  float uacc[4] = {0.f, 0.f, 0.f, 0.f};
  float trep[4] = {0.f, 0.f, 0.f, 0.f};

#pragma unroll
  for (int i = 0; i < 8; ++i) {
    const int rep = i >> 2, m = i & 3;
    f32x4* qc = (i & 1) ? qB : qA;
    f32x4* qn = (i & 1) ? qA : qB;

    // convert current tile (qc dies here)
    u32x4 ahi[4], alo[4];
    cvt8t(qc[0], qc[1], ahi[0], alo[0]);
    cvt8t(qc[2], qc[3], ahi[1], alo[1]);
    cvt8t(qc[4], qc[5], ahi[2], alo[2]);
    cvt8t(qc[6], qc[7], ahi[3], alo[3]);

    // prefetch next tile; its s_waitcnt lands at tile i+1's cvt
    if (i < 7) load_tile(i + 1, qn);

    f32x4 acc[4];
#pragma unroll
    for (int nt = 0; nt < 4; ++nt) {
      const float bv = bias[nt];
      acc[nt] = (f32x4){bv, bv, bv, bv};
    }
#pragma unroll
    for (int ks = 0; ks < 4; ++ks) {
      const s16x8 ah = __builtin_bit_cast(s16x8, ahi[ks]);
      const s16x8 al = __builtin_bit_cast(s16x8, alo[ks]);
#pragma unroll
      for (int nt = 0; nt < 4; ++nt) {
        const s16x8 bh = __builtin_bit_cast(s16x8, sB[((ks * 8 + nt * 2 + 0) * 64) + l]);
        const s16x8 bl = __builtin_bit_cast(s16x8, sB[((ks * 8 + nt * 2 + 1) * 64) + l]);
        acc[nt] = __builtin_amdgcn_mfma_f32_16x16x32_bf16(ah, bh, acc[nt], 0, 0, 0);
        acc[nt] = __builtin_amdgcn_mfma_f32_16x16x32_bf16(al, bh, acc[nt], 0, 0, 0);
        acc[nt] = __builtin_amdgcn_mfma_f32_16x16x32_bf16(ah, bl, acc[nt], 0, 0, 0);
      }
    }

    // epilogue: relu + weighted pooling ; C layout: col=lm+16nt, row=m*16+lg*4+e
    const float rw_all = rep ? rat1 : rat0;
#pragma unroll
    for (int e = 0; e < 4; ++e) {
      const int rr = m * 16 + lg * 4 + e;
      const float w = __shfl(rw_all, rr, 64);
#pragma unroll
      for (int nt = 0; nt < 4; ++nt) {
        const float repv = fmaxf(acc[nt][e], 0.f);
        uacc[nt] = fmaf(w, repv, uacc[nt]);
        if (m == 3 && e == 2) trep[nt] = repv;   // row 50 = target (valid on lg==0)
      }
    }

    if (m == 3) {
      // finalize this batch
      const int bb = rep ? b1 : b0;
      float den = fabsf(rw_all);
#pragma unroll
      for (int s = 32; s >= 1; s >>= 1) den += __shfl_xor(den, s, 64);
#pragma unroll
      for (int nt = 0; nt < 4; ++nt) {
        uacc[nt] += __shfl_xor(uacc[nt], 16, 64);
        uacc[nt] += __shfl_xor(uacc[nt], 32, 64);
      }
      const float dinv = den + 1e-8f;
      const float usel = (lg == 0) ? uacc[0] : (lg == 1) ? uacc[1]
                       : (lg == 2) ? uacc[2] : uacc[3];
      user_vec[(size_t)bb * 64 + l] = usel / dinv;
      if (l < 16) {
        float* tp = target_rep + (size_t)bb * 64 + l;
        tp[0]  = trep[0];
        tp[16] = trep[1];
        tp[32] = trep[2];
        tp[48] = trep[3];
      }
#pragma unroll
      for (int nt = 0; nt < 4; ++nt) { uacc[nt] = 0.f; trep[nt] = 0.f; }
    }

    // cap scheduler pressure: no cross-tile hoisting bulges
    __builtin_amdgcn_sched_barrier(0);
  }
}

// ---------------- kernel C: rating MLP ----------------
__global__ __launch_bounds__(256) void mlp_k(
    const float* __restrict__ user_vec, const float* __restrict__ target_rep,
    const float* __restrict__ w1, const float* __restrict__ b1,
    const float* __restrict__ w2, const float* __restrict__ b2,
    const float* __restrict__ w3, const float* __restrict__ b3,
    float* __restrict__ out)
{
  __shared__ alignas(16) float s_w1[128 * 64];  // 32 KB
  __shared__ alignas(16) float s_w2[64 * 32];   //  8 KB
  __shared__ float s_w3[32];
  __shared__ alignas(16) float s_x[4][128];
  __shared__ alignas(16) float s_h1[4][64];
  const int tid = threadIdx.x;
  for (int i = tid; i < 128 * 64; i += 256) s_w1[i] = w1[i];
  for (int i = tid; i < 64 * 32;  i += 256) s_w2[i] = w2[i];
  if (tid < 32) s_w3[tid] = w3[tid];
  __syncthreads();

  const int t  = tid & 63;
  const int wv = tid >> 6;
  const int nwaves = gridDim.x << 2;
  const float b1t = b1[t];
  const float bb3 = b3[0];
  const int n2 = t & 31;
  const float b2n = b2[n2];
  for (int b = (blockIdx.x << 2) + wv; b < NB; b += nwaves) {
    s_x[wv][t]      = user_vec[(size_t)b * 64 + t];
    s_x[wv][64 + t] = target_rep[(size_t)b * 64 + t];
    float a0 = b1t, a1 = 0.f, a2 = 0.f, a3 = 0.f;
#pragma unroll
    for (int k4 = 0; k4 < 32; ++k4) {
      float4 x = *reinterpret_cast<const float4*>(&s_x[wv][k4 * 4]);
      a0 = fmaf(x.x, s_w1[(4 * k4 + 0) * 64 + t], a0);
      a1 = fmaf(x.y, s_w1[(4 * k4 + 1) * 64 + t], a1);
      a2 = fmaf(x.z, s_w1[(4 * k4 + 2) * 64 + t], a2);
      a3 = fmaf(x.w, s_w1[(4 * k4 + 3) * 64 + t], a3);
    }
    s_h1[wv][t] = fmaxf((a0 + a1) + (a2 + a3), 0.f);
    float c0 = b2n, c1 = 0.f, c2 = 0.f, c3 = 0.f;
#pragma unroll
    for (int k4 = 0; k4 < 16; ++k4) {
      float4 x = *reinterpret_cast<const float4*>(&s_h1[wv][k4 * 4]);
      c0 = fmaf(x.x, s_w2[(4 * k4 + 0) * 32 + n2], c0);
      c1 = fmaf(x.y, s_w2[(4 * k4 + 1) * 32 + n2], c1);
      c2 = fmaf(x.z, s_w2[(4 * k4 + 2) * 32 + n2], c2);
      c3 = fmaf(x.w, s_w2[(4 * k4 + 3) * 32 + n2], c3);
    }
    const float h2 = fmaxf((c0 + c1) + (c2 + c3), 0.f);
    float p = (t < 32) ? h2 * s_w3[n2] : 0.f;
#pragma unroll
    for (int m = 32; m >= 1; m >>= 1) p += __shfl_xor(p, m, 64);
    if (t == 0) out[b] = p + bb3;
  }
}

extern "C" void kernel_launch(void* const* d_in, const int* in_sizes, int n_in,
                              void* d_out, int out_size, void* d_ws, size_t ws_size,
                              hipStream_t stream) {
  const int*   hidx  = (const int*)  d_in[0];
  const float* hfeat = (const float*)d_in[1];
  const float* hrat  = (const float*)d_in[2];
  const int*   tidx  = (const int*)  d_in[3];
  const float* tfeat = (const float*)d_in[4];
  const float* table = (const float*)d_in[5];
  const float* fw    = (const float*)d_in[6];
  const float* fb    = (const float*)d_in[7];
  const float* w1    = (const float*)d_in[8];
  const float* b1    = (const float*)d_in[9];
  const float* w2    = (const float*)d_in[10];
  const float* b2    = (const float*)d_in[11];
  const float* w3    = (const float*)d_in[12];
  const float* b3    = (const float*)d_in[13];
  float* out = (float*)d_out;
  float* ws  = (float*)d_ws;
  unsigned* bfrag   = (unsigned*)ws;      // 8192 dwords
  float* user_vec   = ws + 6400000;
  float* target_rep = ws + 7448576;

  hipLaunchKernelGGL(wprep_k, dim3(32), dim3(256), 0, stream, fw, bfrag);
  hipLaunchKernelGGL(pool_mfma_k, dim3(2048), dim3(256), 0, stream,
                     hidx, hfeat, hrat, tidx, tfeat, table, fb, bfrag,
                     user_vec, target_rep);
  hipLaunchKernelGGL(mlp_k, dim3(512), dim3(256), 0, stream,
                     user_vec, target_rep, w1, b1, w2, b2, w3, b3, out);
}